// Round 1
// baseline (548.709 us; speedup 1.0000x reference)
//
#include <hip/hip_runtime.h>

// Problem constants
#define NPATCH 15376      // 124*124 patches per image
#define KDIM   75         // 3*5*5 features per patch
#define NP     15488      // X rows padded to 121*128
#define MP     15424      // Y cols padded to 241*64
#define TM     128        // rows per block tile
#define TN     64         // cols per iteration tile
#define NC     8          // column chunks (grid.y)
#define CTILES 241        // MP / TN
#define TPC    31         // col-tiles per chunk (31*8 >= 241)

// ---------------- unfold: img [1,3,128,128] -> dst[k][patch] (k-major) ----------------
__global__ void unfold_kernel(const float* __restrict__ img,
                              float* __restrict__ dst,
                              int stride, int total) {
    int idx = blockIdx.x * 256 + threadIdx.x;
    if (idx >= total) return;
    int f = idx / stride;          // feature 0..74
    int l = idx - f * stride;      // patch index (padded range)
    float v = 0.0f;
    if (l < NPATCH) {
        int ch  = f / 25;
        int rem = f - ch * 25;
        int di  = rem / 5;
        int dj  = rem - di * 5;
        int r   = l / 124;
        int c   = l - r * 124;
        v = img[ch * 16384 + (r + di) * 128 + (c + dj)];
    }
    dst[idx] = v;
}

// ---------------- squared norms per patch (column sums of k-major matrix) ----------------
__global__ void sqnorm_kernel(const float* __restrict__ mat,
                              float* __restrict__ out,
                              int stride, float padval) {
    int pi = blockIdx.x * 256 + threadIdx.x;
    if (pi >= stride) return;
    if (pi >= NPATCH) { out[pi] = padval; return; }
    float s = 0.0f;
    #pragma unroll
    for (int k = 0; k < KDIM; ++k) {
        float v = mat[k * stride + pi];
        s = fmaf(v, v, s);
    }
    out[pi] = s;
}

// ---------------- fused dist-GEMM + per-row min/argmin over a column chunk ----------------
__global__ __launch_bounds__(256, 2)
void dist_kernel(const float* __restrict__ XT,
                 const float* __restrict__ YT,
                 const float* __restrict__ Y2g,
                 float* __restrict__ pmin,
                 int* __restrict__ pidx) {
    __shared__ float Xs[KDIM][TM];   // 38400 B
    __shared__ float Ys[KDIM][TN];   // 19200 B
    __shared__ float Y2s[TN];

    const int rt    = blockIdx.x;    // row tile 0..120
    const int chunk = blockIdx.y;    // 0..7
    const int i0    = rt * TM;
    const int tid   = threadIdx.x;

    // Load X tile once (float4, coalesced): 75*128/4 = 2400 vec4
    for (int v = tid; v < KDIM * TM / 4; v += 256) {
        int k  = v >> 5;              // / (TM/4=32)
        int c4 = v & 31;
        *(float4*)&Xs[k][c4 * 4] = *(const float4*)&XT[k * NP + i0 + c4 * 4];
    }

    const int lane = tid & 63;
    const int tc   = lane & 15;            // 0..15 -> 4 cols each
    const int tr   = (tid >> 6) * 4 + (lane >> 4);  // 0..15 -> 8 rows each
    const int rbase = tr * 8;
    const int cbase = tc * 4;

    float mn[8];
    int   mi[8];
    #pragma unroll
    for (int r = 0; r < 8; ++r) { mn[r] = 3.4e38f; mi[r] = 0x7fffffff; }

    const int t0 = chunk * TPC;
    const int t1 = (t0 + TPC < CTILES) ? (t0 + TPC) : CTILES;

    for (int ct = t0; ct < t1; ++ct) {
        const int j0 = ct * TN;
        __syncthreads();   // protect Ys/Y2s reuse from previous iteration
        // Load Y tile (float4, coalesced): 75*64/4 = 1200 vec4
        for (int v = tid; v < KDIM * TN / 4; v += 256) {
            int k  = v >> 4;          // / (TN/4=16)
            int c4 = v & 15;
            *(float4*)&Ys[k][c4 * 4] = *(const float4*)&YT[k * MP + j0 + c4 * 4];
        }
        if (tid < TN) Y2s[tid] = Y2g[j0 + tid];
        __syncthreads();

        float acc[8][4];
        #pragma unroll
        for (int r = 0; r < 8; ++r)
            #pragma unroll
            for (int c = 0; c < 4; ++c) acc[r][c] = 0.0f;

        #pragma unroll 5
        for (int k = 0; k < KDIM; ++k) {
            float4 xa = *(float4*)&Xs[k][rbase];
            float4 xb = *(float4*)&Xs[k][rbase + 4];
            float4 yv = *(float4*)&Ys[k][cbase];
            float xr[8] = {xa.x, xa.y, xa.z, xa.w, xb.x, xb.y, xb.z, xb.w};
            float yc[4] = {yv.x, yv.y, yv.z, yv.w};
            #pragma unroll
            for (int r = 0; r < 8; ++r)
                #pragma unroll
                for (int c = 0; c < 4; ++c)
                    acc[r][c] = fmaf(xr[r], yc[c], acc[r][c]);
        }

        #pragma unroll
        for (int c = 0; c < 4; ++c) {
            const int   j  = j0 + cbase + c;
            const float y2 = Y2s[cbase + c];
            #pragma unroll
            for (int r = 0; r < 8; ++r) {
                float d = fmaf(-2.0f, acc[r][c], y2);
                if (d < mn[r]) { mn[r] = d; mi[r] = j; }
            }
        }
    }

    // Reduce min/argmin across the 16 lanes (tc) sharing the same rows.
    #pragma unroll
    for (int r = 0; r < 8; ++r) {
        float m  = mn[r];
        int   id = mi[r];
        #pragma unroll
        for (int off = 1; off < 16; off <<= 1) {
            float om = __shfl_xor(m, off);
            int   oi = __shfl_xor(id, off);
            if (om < m || (om == m && oi < id)) { m = om; id = oi; }
        }
        if (tc == 0) {
            int row = i0 + rbase + r;
            pmin[row * NC + chunk] = m;
            pidx[row * NC + chunk] = id;
        }
    }
}

// ---------------- finalize: reduce chunks per row, write idx, partial loss sums ----------------
__global__ void finalize_kernel(const float* __restrict__ pmin,
                                const int* __restrict__ pidx,
                                const float* __restrict__ X2,
                                float* __restrict__ out,
                                float* __restrict__ partial) {
    __shared__ float sdata[256];
    int row = blockIdx.x * 256 + threadIdx.x;
    float nn = 0.0f;
    if (row < NPATCH) {
        float m  = pmin[row * NC];
        int   id = pidx[row * NC];
        #pragma unroll
        for (int c = 1; c < NC; ++c) {
            float om = pmin[row * NC + c];
            int   oi = pidx[row * NC + c];
            if (om < m || (om == m && oi < id)) { m = om; id = oi; }
        }
        out[1 + row] = (float)id;      // nn_idx as float
        nn = X2[row] + m;              // full distance
    }
    sdata[threadIdx.x] = nn;
    __syncthreads();
    for (int s = 128; s > 0; s >>= 1) {
        if (threadIdx.x < s) sdata[threadIdx.x] += sdata[threadIdx.x + s];
        __syncthreads();
    }
    if (threadIdx.x == 0) partial[blockIdx.x] = sdata[0];
}

// ---------------- deterministic final loss ----------------
__global__ void loss_kernel(const float* __restrict__ partial, int nparts,
                            float* __restrict__ out) {
    int l = threadIdx.x;  // 64 threads
    float s = (l < nparts) ? partial[l] : 0.0f;
    #pragma unroll
    for (int off = 32; off > 0; off >>= 1) s += __shfl_down(s, off);
    if (l == 0) out[0] = s / (float)NPATCH;
}

extern "C" void kernel_launch(void* const* d_in, const int* in_sizes, int n_in,
                              void* d_out, int out_size, void* d_ws, size_t ws_size,
                              hipStream_t stream) {
    const float* crop = (const float*)d_in[0];
    const float* orig = (const float*)d_in[1];
    float* out = (float*)d_out;
    float* ws  = (float*)d_ws;

    float* XT = ws;                         // 75*15488
    float* YT = XT + KDIM * NP;             // 75*15424
    float* X2 = YT + KDIM * MP;             // 15488
    float* Y2 = X2 + NP;                    // 15424
    float* PM = Y2 + MP;                    // 15488*8
    int*   PI = (int*)(PM + NP * NC);       // 15488*8
    float* PART = (float*)(PI + NP * NC);   // 64

    unfold_kernel<<<(KDIM * NP + 255) / 256, 256, 0, stream>>>(crop, XT, NP, KDIM * NP);
    unfold_kernel<<<(KDIM * MP + 255) / 256, 256, 0, stream>>>(orig, YT, MP, KDIM * MP);
    sqnorm_kernel<<<(NP + 255) / 256, 256, 0, stream>>>(XT, X2, NP, 0.0f);
    sqnorm_kernel<<<(MP + 255) / 256, 256, 0, stream>>>(YT, Y2, MP, 3.0e38f);

    dim3 dgrid(121, NC);
    dist_kernel<<<dgrid, 256, 0, stream>>>(XT, YT, Y2, PM, PI);

    finalize_kernel<<<(NPATCH + 255) / 256, 256, 0, stream>>>(PM, PI, X2, out, PART);
    loss_kernel<<<1, 64, 0, stream>>>(PART, 61, out);
}

// Round 4
// 349.123 us; speedup vs baseline: 1.5717x; 1.5717x over previous
//
#include <hip/hip_runtime.h>
#include <hip/hip_bf16.h>

#define NPATCH 15376      // 124*124 patches
#define NP     15488      // padded to 121*128
#define NT     121        // column tiles (128 cols each)
#define KP     256        // packed K: [0,75)=hi*hi, [75,150)=hi*lo, [150,225)=lo*hi, pad 0
#define BM     128
#define BK     64
#define EPS    0.25f
#define NRBLK  3844       // 15376/4 repair blocks

typedef __attribute__((ext_vector_type(8))) __bf16 bf16x8;
typedef __attribute__((ext_vector_type(4))) float  f32x4;

__device__ __forceinline__ void gload_lds16(const void* g, void* l) {
    __builtin_amdgcn_global_load_lds((const __attribute__((address_space(1))) unsigned int*)g,
                                     (__attribute__((address_space(3))) unsigned int*)l, 16, 0, 0);
}

__device__ __forceinline__ unsigned short f2bf(float x) {
    __hip_bfloat16 h = __float2bfloat16(x);
    return *(unsigned short*)&h;
}
__device__ __forceinline__ float bf2f(unsigned short u) {
    __hip_bfloat16 h; *(unsigned short*)&h = u;
    return __bfloat162float(h);
}

// ---------- pack: image -> bf16 split matrix [NP][KP].  mode 0: A(hi,hi,lo)  mode 1: B(hi,lo,hi)
__global__ void pack_kernel(const float* __restrict__ img, unsigned short* __restrict__ dst, int mode) {
    int idx = blockIdx.x * 256 + threadIdx.x;        // r*256 + c
    int r = idx >> 8, c = idx & 255;
    unsigned short v = 0;
    if (r < NPATCH && c < 225) {
        int seg, f;
        if (c < 75)       { seg = 0; f = c; }
        else if (c < 150) { seg = 1; f = c - 75; }
        else              { seg = 2; f = c - 150; }
        int ch = f / 25, rem = f % 25, di = rem / 5, dj = rem % 5;
        int pr = r / 124, pc = r % 124;
        float x = img[ch * 16384 + (pr + di) * 128 + (pc + dj)];
        unsigned short hi = f2bf(x);
        float hf = bf2f(hi);
        unsigned short lo = f2bf(x - hf);
        bool want_hi = (mode == 0) ? (seg <= 1) : (seg != 1);
        v = want_hi ? hi : lo;
    }
    dst[idx] = v;
}

// ---------- squared norms straight from the image
__global__ void sqnorm_img(const float* __restrict__ img, float* __restrict__ out, int n) {
    int p = blockIdx.x * 256 + threadIdx.x;
    if (p >= n) return;
    if (p >= NPATCH) { out[p] = 3.0e38f; return; }
    int pr = p / 124, pc = p % 124;
    const float* base = img + pr * 128 + pc;
    float s = 0.f;
    #pragma unroll
    for (int ch = 0; ch < 3; ++ch)
        #pragma unroll
        for (int di = 0; di < 5; ++di)
            #pragma unroll
            for (int dj = 0; dj < 5; ++dj) {
                float v = base[ch * 16384 + di * 128 + dj];
                s = fmaf(v, v, s);
            }
    out[p] = s;
}

// ---------- MFMA dist screen: per (row, 128-col block) min of (Y2 - 2*dot)
__global__ __launch_bounds__(256, 2)
void dist_mfma(const unsigned short* __restrict__ A, const unsigned short* __restrict__ B,
               const float* __restrict__ Y2, float* __restrict__ PM) {
    __shared__ __align__(16) unsigned short As[2][BM][BK];   // 32 KB
    __shared__ __align__(16) unsigned short Bs[2][BM][BK];   // 32 KB

    const int tid = threadIdx.x, lane = tid & 63, wid = tid >> 6;
    const int wr = wid >> 1, wc = wid & 1;
    const int i0 = blockIdx.x * BM, j0 = blockIdx.y * BM;

    f32x4 acc[4][4];
    #pragma unroll
    for (int mi = 0; mi < 4; ++mi)
        #pragma unroll
        for (int ni = 0; ni < 4; ++ni)
            acc[mi][ni] = (f32x4){0.f, 0.f, 0.f, 0.f};

    const int srow = (lane >> 3);          // 0..7 within chunk
    const int scol = (lane & 7) * 8;       // 0..56

    #define STAGE(buf, kt)                                                            \
        {                                                                             \
            int k0_ = (kt) * BK;                                                      \
            _Pragma("unroll")                                                         \
            for (int i_ = 0; i_ < 4; ++i_) {                                          \
                int c_ = wid * 4 + i_;                                                \
                int row_ = c_ * 8 + srow;                                             \
                gload_lds16(A + (size_t)(i0 + row_) * KP + k0_ + scol, &As[buf][c_ * 8][0]); \
                gload_lds16(B + (size_t)(j0 + row_) * KP + k0_ + scol, &Bs[buf][c_ * 8][0]); \
            }                                                                         \
        }

    STAGE(0, 0);
    asm volatile("s_waitcnt vmcnt(0)" ::: "memory");
    __syncthreads();

    int cur = 0;
    for (int kt = 0; kt < 4; ++kt) {
        if (kt < 3) STAGE(cur ^ 1, kt + 1);
        #pragma unroll
        for (int ks = 0; ks < 2; ++ks) {
            bf16x8 a[4], b[4];
            #pragma unroll
            for (int mi = 0; mi < 4; ++mi)
                a[mi] = *(const bf16x8*)&As[cur][wr * 64 + mi * 16 + (lane & 15)][ks * 32 + (lane >> 4) * 8];
            #pragma unroll
            for (int ni = 0; ni < 4; ++ni)
                b[ni] = *(const bf16x8*)&Bs[cur][wc * 64 + ni * 16 + (lane & 15)][ks * 32 + (lane >> 4) * 8];
            #pragma unroll
            for (int mi = 0; mi < 4; ++mi)
                #pragma unroll
                for (int ni = 0; ni < 4; ++ni)
                    acc[mi][ni] = __builtin_amdgcn_mfma_f32_16x16x32_bf16(a[mi], b[ni], acc[mi][ni], 0, 0, 0);
        }
        asm volatile("s_waitcnt vmcnt(0)" ::: "memory");
        __syncthreads();
        cur ^= 1;
    }

    // Epilogue: d = Y2[col] - 2*acc; per-row min over this block's 128 cols.
    float y2v[4];
    #pragma unroll
    for (int ni = 0; ni < 4; ++ni)
        y2v[ni] = Y2[j0 + wc * 64 + ni * 16 + (lane & 15)];

    float* Ms = (float*)&As[0][0][0];   // [2][128] (As dead after last barrier)
    #pragma unroll
    for (int mi = 0; mi < 4; ++mi) {
        #pragma unroll
        for (int j = 0; j < 4; ++j) {
            float m = fmaf(-2.f, acc[mi][0][j], y2v[0]);
            #pragma unroll
            for (int ni = 1; ni < 4; ++ni)
                m = fminf(m, fmaf(-2.f, acc[mi][ni][j], y2v[ni]));
            #pragma unroll
            for (int off = 1; off < 16; off <<= 1)
                m = fminf(m, __shfl_xor(m, off));
            if ((lane & 15) == 0)
                Ms[wc * 128 + wr * 64 + mi * 16 + (lane >> 4) * 4 + j] = m;
        }
    }
    __syncthreads();
    if (tid < 128) {
        float pm = fminf(Ms[tid], Ms[128 + tid]);
        PM[(size_t)blockIdx.y * NP + i0 + tid] = pm;
    }
}

// ---------- repair: exact f32 argmin over flagged col-blocks (one wave per row)
// Each lane covers TWO column tiles: lane and lane+64 (NT=121 > 64 lanes).
__global__ void repair_kernel(const float* __restrict__ crop, const float* __restrict__ orig,
                              const float* __restrict__ X2, const float* __restrict__ Y2,
                              const float* __restrict__ PM,
                              float* __restrict__ out, float* __restrict__ partial) {
    __shared__ float psum[4];
    const int tid = threadIdx.x, lane = tid & 63, wid = tid >> 6;
    const int r = blockIdx.x * 4 + wid;               // always < NPATCH (3844*4)

    float pm0 = PM[(size_t)lane * NP + r];                                        // tiles 0..63
    float pm1 = (lane + 64 < NT) ? PM[(size_t)(lane + 64) * NP + r] : 3.4e38f;    // tiles 64..120
    float mt = fminf(pm0, pm1);
    #pragma unroll
    for (int off = 1; off < 64; off <<= 1)
        mt = fminf(mt, __shfl_xor(mt, off));
    unsigned long long mask0 = __ballot(pm0 <= mt + EPS);
    unsigned long long mask1 = __ballot((lane + 64 < NT) && pm1 <= mt + EPS);

    const float x2 = X2[r];
    const int pr = r / 124, pc = r % 124;
    const float* xbase = crop + pr * 128 + pc;

    float bestd = 3.4e38f;
    int   besti = 0x7fffffff;
    #pragma unroll
    for (int half = 0; half < 2; ++half) {
        unsigned long long mask = half ? mask1 : mask0;
        const int toff = half * 64;
        while (mask) {
            int ct = (__ffsll(mask) - 1) + toff;
            mask &= mask - 1;
            int jb = ct * 128;
            #pragma unroll
            for (int h = 0; h < 2; ++h) {
                int j = jb + h * 64 + lane;
                float d = 3.4e38f;
                int   ji = 0x7fffffff;
                if (j < NPATCH) {
                    int jr = j / 124, jc = j % 124;
                    const float* ybase = orig + jr * 128 + jc;
                    float dot = 0.f;
                    #pragma unroll
                    for (int ch = 0; ch < 3; ++ch)
                        #pragma unroll
                        for (int di = 0; di < 5; ++di)
                            #pragma unroll
                            for (int dj = 0; dj < 5; ++dj)
                                dot = fmaf(xbase[ch * 16384 + di * 128 + dj],
                                           ybase[ch * 16384 + di * 128 + dj], dot);
                    d  = fmaf(-2.f, dot, x2) + Y2[j];
                    ji = j;
                }
                if (d < bestd || (d == bestd && ji < besti)) { bestd = d; besti = ji; }
            }
        }
    }
    #pragma unroll
    for (int off = 1; off < 64; off <<= 1) {
        float od = __shfl_xor(bestd, off);
        int   oi = __shfl_xor(besti, off);
        if (od < bestd || (od == bestd && oi < besti)) { bestd = od; besti = oi; }
    }
    if (lane == 0) {
        out[1 + r] = (float)besti;
        psum[wid] = bestd;
    }
    __syncthreads();
    if (tid == 0) partial[blockIdx.x] = (psum[0] + psum[1]) + (psum[2] + psum[3]);
}

// ---------- deterministic final loss
__global__ void loss_final(const float* __restrict__ partial, float* __restrict__ out) {
    __shared__ float s[256];
    float acc = 0.f;
    for (int i = threadIdx.x; i < NRBLK; i += 256) acc += partial[i];
    s[threadIdx.x] = acc;
    __syncthreads();
    for (int st = 128; st > 0; st >>= 1) {
        if (threadIdx.x < st) s[threadIdx.x] += s[threadIdx.x + st];
        __syncthreads();
    }
    if (threadIdx.x == 0) out[0] = s[0] / (float)NPATCH;
}

extern "C" void kernel_launch(void* const* d_in, const int* in_sizes, int n_in,
                              void* d_out, int out_size, void* d_ws, size_t ws_size,
                              hipStream_t stream) {
    const float* crop = (const float*)d_in[0];
    const float* orig = (const float*)d_in[1];
    float* out = (float*)d_out;

    unsigned short* Abig = (unsigned short*)d_ws;              // NP*KP
    unsigned short* Bbig = Abig + (size_t)NP * KP;             // NP*KP
    float* X2 = (float*)(Bbig + (size_t)NP * KP);              // NPATCH
    float* Y2 = X2 + NPATCH;                                   // NP (pads = 3e38)
    float* PM = Y2 + NP;                                       // NT*NP
    float* PART = PM + (size_t)NT * NP;                        // NRBLK

    pack_kernel<<<NP, 256, 0, stream>>>(crop, Abig, 0);
    pack_kernel<<<NP, 256, 0, stream>>>(orig, Bbig, 1);
    sqnorm_img<<<(NPATCH + 255) / 256, 256, 0, stream>>>(crop, X2, NPATCH);
    sqnorm_img<<<(NP + 255) / 256, 256, 0, stream>>>(orig, Y2, NP);

    dim3 dgrid(NT, NT);
    dist_mfma<<<dgrid, 256, 0, stream>>>(Abig, Bbig, Y2, PM);

    repair_kernel<<<NRBLK, 256, 0, stream>>>(crop, orig, X2, Y2, PM, out, PART);
    loss_final<<<1, 256, 0, stream>>>(PART, out);
}

// Round 5
// 248.461 us; speedup vs baseline: 2.2084x; 1.4051x over previous
//
#include <hip/hip_runtime.h>
#include <hip/hip_bf16.h>

#define NPATCH 15376      // 124*124 patches
#define NP     15488      // padded to 121*128
#define NT     121        // tiles per dim (128 rows/cols each)
#define KS     12         // 16B k-chunks per row (96 bf16 features, 75 used)
#define TILE_SHORTS 12288 // 12*128*8 shorts per tile (24KB)
#define EPS    4.0f       // covers 2x deterministic hi-only screen error bound
#define NRBLK  3844       // 15376/4 repair blocks

typedef __attribute__((ext_vector_type(8))) __bf16 bf16x8;
typedef __attribute__((ext_vector_type(4))) float  f32x4;

__device__ __forceinline__ void gload_lds16(const void* g, void* l) {
    __builtin_amdgcn_global_load_lds((const __attribute__((address_space(1))) unsigned int*)g,
                                     (__attribute__((address_space(3))) unsigned int*)l, 16, 0, 0);
}

__device__ __forceinline__ unsigned short f2bf(float x) {
    __hip_bfloat16 h = __float2bfloat16(x);
    return *(unsigned short*)&h;
}

// ---------- pack: image -> bf16-hi, tile-major K-chunk layout.
// Flat short index = ((tile*12 + kslot)*128 + rowin)*8 + e  == cid*8 + e.
// This is byte-identical to the dist kernel's LDS layout -> staging is a linear memcpy.
__global__ void pack_kernel(const float* __restrict__ img, unsigned short* __restrict__ dst) {
    int cid = blockIdx.x * 256 + threadIdx.x;       // 0 .. 121*12*128-1
    int t   = cid / 1536;
    int rem = cid - t * 1536;
    int s   = rem >> 7;          // kslot 0..11
    int r   = rem & 127;         // row within tile
    int row = t * 128 + r;       // patch index (padded range)

    unsigned short ch8[8];
    #pragma unroll
    for (int e = 0; e < 8; ++e) {
        int k = s * 8 + e;
        unsigned short v = 0;
        if (row < NPATCH && k < 75) {
            int c  = k / 25, rem2 = k - c * 25;
            int di = rem2 / 5, dj = rem2 - di * 5;
            int pr = row / 124, pc = row - pr * 124;
            v = f2bf(img[c * 16384 + (pr + di) * 128 + (pc + dj)]);
        }
        ch8[e] = v;
    }
    *(ulonglong2*)(dst + (size_t)cid * 8) = *(ulonglong2*)ch8;
}

// ---------- squared norms straight from the image (exact f32)
__global__ void sqnorm_img(const float* __restrict__ img, float* __restrict__ out, int n) {
    int p = blockIdx.x * 256 + threadIdx.x;
    if (p >= n) return;
    if (p >= NPATCH) { out[p] = 3.0e38f; return; }
    int pr = p / 124, pc = p % 124;
    const float* base = img + pr * 128 + pc;
    float s = 0.f;
    #pragma unroll
    for (int ch = 0; ch < 3; ++ch)
        #pragma unroll
        for (int di = 0; di < 5; ++di)
            #pragma unroll
            for (int dj = 0; dj < 5; ++dj) {
                float v = base[ch * 16384 + di * 128 + dj];
                s = fmaf(v, v, s);
            }
    out[p] = s;
}

// ---------- MFMA hi-only dist screen: per (row, 128-col block) min of (Y2 - 2*dot_hi)
__global__ __launch_bounds__(256, 3)
void dist_mfma(const unsigned short* __restrict__ A, const unsigned short* __restrict__ B,
               const float* __restrict__ Y2, float* __restrict__ PM) {
    __shared__ __align__(16) unsigned short As[KS][128][8];   // 24 KB
    __shared__ __align__(16) unsigned short Bs[KS][128][8];   // 24 KB

    const int tid = threadIdx.x, lane = tid & 63, wid = tid >> 6;
    const int wr = wid >> 1, wc = wid & 1;

    // bijective XCD chunk swizzle (nwg = 14641 = 8*1830 + 1)
    const int orig = blockIdx.x;
    const int xcd = orig & 7, idx = orig >> 3;
    const int q = 1830, rm = 1;
    const int wg = ((xcd < rm) ? xcd * (q + 1) : rm * (q + 1) + (xcd - rm) * q) + idx;
    const int bx = wg % NT, by = wg / NT;   // bx = A row-tile (fast), by = B col-tile
    const int i0 = bx * 128, j0 = by * 128;

    // Stage both 24KB tiles linearly (global layout == LDS layout).
    const char* Ag = (const char*)(A + (size_t)bx * TILE_SHORTS);
    const char* Bg = (const char*)(B + (size_t)by * TILE_SHORTS);
    char* Al = (char*)&As[0][0][0];
    char* Bl = (char*)&Bs[0][0][0];
    #pragma unroll
    for (int i = 0; i < 6; ++i) {
        int v = wid * 6 + i;                  // 24 wave-loads of 1KB per matrix
        gload_lds16(Ag + v * 1024 + lane * 16, Al + v * 1024);
        gload_lds16(Bg + v * 1024 + lane * 16, Bl + v * 1024);
    }
    asm volatile("s_waitcnt vmcnt(0)" ::: "memory");
    __syncthreads();

    f32x4 acc[4][4];
    #pragma unroll
    for (int mi = 0; mi < 4; ++mi)
        #pragma unroll
        for (int ni = 0; ni < 4; ++ni)
            acc[mi][ni] = (f32x4){0.f, 0.f, 0.f, 0.f};

    #pragma unroll
    for (int ks = 0; ks < 3; ++ks) {
        bf16x8 a[4], b[4];
        #pragma unroll
        for (int mi = 0; mi < 4; ++mi)
            a[mi] = *(const bf16x8*)&As[ks * 4 + (lane >> 4)][wr * 64 + mi * 16 + (lane & 15)][0];
        #pragma unroll
        for (int ni = 0; ni < 4; ++ni)
            b[ni] = *(const bf16x8*)&Bs[ks * 4 + (lane >> 4)][wc * 64 + ni * 16 + (lane & 15)][0];
        #pragma unroll
        for (int mi = 0; mi < 4; ++mi)
            #pragma unroll
            for (int ni = 0; ni < 4; ++ni)
                acc[mi][ni] = __builtin_amdgcn_mfma_f32_16x16x32_bf16(a[mi], b[ni], acc[mi][ni], 0, 0, 0);
    }

    // Epilogue: d = Y2[col] - 2*acc; per-row min over this block's 128 cols.
    float y2v[4];
    #pragma unroll
    for (int ni = 0; ni < 4; ++ni)
        y2v[ni] = Y2[j0 + wc * 64 + ni * 16 + (lane & 15)];

    float* Ms = (float*)&As[0][0][0];   // 256 floats, As dead after barrier
    __syncthreads();
    #pragma unroll
    for (int mi = 0; mi < 4; ++mi) {
        #pragma unroll
        for (int j = 0; j < 4; ++j) {
            float m = fmaf(-2.f, acc[mi][0][j], y2v[0]);
            #pragma unroll
            for (int ni = 1; ni < 4; ++ni)
                m = fminf(m, fmaf(-2.f, acc[mi][ni][j], y2v[ni]));
            #pragma unroll
            for (int off = 1; off < 16; off <<= 1)
                m = fminf(m, __shfl_xor(m, off));
            if ((lane & 15) == 0)
                Ms[wc * 128 + wr * 64 + mi * 16 + (lane >> 4) * 4 + j] = m;
        }
    }
    __syncthreads();
    if (tid < 128) {
        float pm = fminf(Ms[tid], Ms[128 + tid]);
        PM[(size_t)by * NP + i0 + tid] = pm;
    }
}

// ---------- repair: exact f32 argmin over flagged col-blocks (one wave per row)
// Each lane covers TWO column tiles: lane and lane+64 (NT=121 > 64 lanes).
__global__ void repair_kernel(const float* __restrict__ crop, const float* __restrict__ orig,
                              const float* __restrict__ X2, const float* __restrict__ Y2,
                              const float* __restrict__ PM,
                              float* __restrict__ out, float* __restrict__ partial) {
    __shared__ float psum[4];
    const int tid = threadIdx.x, lane = tid & 63, wid = tid >> 6;
    const int r = blockIdx.x * 4 + wid;               // always < NPATCH (3844*4)

    float pm0 = PM[(size_t)lane * NP + r];                                        // tiles 0..63
    float pm1 = (lane + 64 < NT) ? PM[(size_t)(lane + 64) * NP + r] : 3.4e38f;    // tiles 64..120
    float mt = fminf(pm0, pm1);
    #pragma unroll
    for (int off = 1; off < 64; off <<= 1)
        mt = fminf(mt, __shfl_xor(mt, off));
    unsigned long long mask0 = __ballot(pm0 <= mt + EPS);
    unsigned long long mask1 = __ballot((lane + 64 < NT) && pm1 <= mt + EPS);

    const float x2 = X2[r];
    const int pr = r / 124, pc = r % 124;
    const float* xbase = crop + pr * 128 + pc;

    float bestd = 3.4e38f;
    int   besti = 0x7fffffff;
    #pragma unroll
    for (int half = 0; half < 2; ++half) {
        unsigned long long mask = half ? mask1 : mask0;
        const int toff = half * 64;
        while (mask) {
            int ct = (__ffsll(mask) - 1) + toff;
            mask &= mask - 1;
            int jb = ct * 128;
            #pragma unroll
            for (int h = 0; h < 2; ++h) {
                int j = jb + h * 64 + lane;
                float d = 3.4e38f;
                int   ji = 0x7fffffff;
                if (j < NPATCH) {
                    int jr = j / 124, jc = j % 124;
                    const float* ybase = orig + jr * 128 + jc;
                    float dot = 0.f;
                    #pragma unroll
                    for (int ch = 0; ch < 3; ++ch)
                        #pragma unroll
                        for (int di = 0; di < 5; ++di)
                            #pragma unroll
                            for (int dj = 0; dj < 5; ++dj)
                                dot = fmaf(xbase[ch * 16384 + di * 128 + dj],
                                           ybase[ch * 16384 + di * 128 + dj], dot);
                    d  = fmaf(-2.f, dot, x2) + Y2[j];
                    ji = j;
                }
                if (d < bestd || (d == bestd && ji < besti)) { bestd = d; besti = ji; }
            }
        }
    }
    #pragma unroll
    for (int off = 1; off < 64; off <<= 1) {
        float od = __shfl_xor(bestd, off);
        int   oi = __shfl_xor(besti, off);
        if (od < bestd || (od == bestd && oi < besti)) { bestd = od; besti = oi; }
    }
    if (lane == 0) {
        out[1 + r] = (float)besti;
        psum[wid] = bestd;
    }
    __syncthreads();
    if (tid == 0) partial[blockIdx.x] = (psum[0] + psum[1]) + (psum[2] + psum[3]);
}

// ---------- deterministic final loss
__global__ void loss_final(const float* __restrict__ partial, float* __restrict__ out) {
    __shared__ float s[256];
    float acc = 0.f;
    for (int i = threadIdx.x; i < NRBLK; i += 256) acc += partial[i];
    s[threadIdx.x] = acc;
    __syncthreads();
    for (int st = 128; st > 0; st >>= 1) {
        if (threadIdx.x < st) s[threadIdx.x] += s[threadIdx.x + st];
        __syncthreads();
    }
    if (threadIdx.x == 0) out[0] = s[0] / (float)NPATCH;
}

extern "C" void kernel_launch(void* const* d_in, const int* in_sizes, int n_in,
                              void* d_out, int out_size, void* d_ws, size_t ws_size,
                              hipStream_t stream) {
    const float* crop = (const float*)d_in[0];
    const float* orig = (const float*)d_in[1];
    float* out = (float*)d_out;

    unsigned short* Abig = (unsigned short*)d_ws;              // NT*12288 shorts
    unsigned short* Bbig = Abig + (size_t)NT * TILE_SHORTS;    // NT*12288 shorts
    float* X2 = (float*)(Bbig + (size_t)NT * TILE_SHORTS);     // NPATCH
    float* Y2 = X2 + NPATCH;                                   // NP (pads = 3e38)
    float* PM = Y2 + NP;                                       // NT*NP
    float* PART = PM + (size_t)NT * NP;                        // NRBLK

    pack_kernel<<<726, 256, 0, stream>>>(crop, Abig);
    pack_kernel<<<726, 256, 0, stream>>>(orig, Bbig);
    sqnorm_img<<<(NPATCH + 255) / 256, 256, 0, stream>>>(crop, X2, NPATCH);
    sqnorm_img<<<(NP + 255) / 256, 256, 0, stream>>>(orig, Y2, NP);

    dist_mfma<<<NT * NT, 256, 0, stream>>>(Abig, Bbig, Y2, PM);

    repair_kernel<<<NRBLK, 256, 0, stream>>>(crop, orig, X2, Y2, PM, out, PART);
    loss_final<<<1, 256, 0, stream>>>(PART, out);
}

// Round 6
// 219.844 us; speedup vs baseline: 2.4959x; 1.1302x over previous
//
#include <hip/hip_runtime.h>
#include <hip/hip_bf16.h>

#define NPATCH 15376      // 124*124 patches
#define NP     15488      // padded to 121*128
#define NT     121        // tiles per dim (128 rows/cols each)
#define KS     12         // 16B k-chunks per row (96 bf16 features, 75 used)
#define TILE_SHORTS 12288 // 12*128*8 shorts per tile (24KB)
#define EPS    4.0f       // covers 2x deterministic hi-only screen error bound

typedef __attribute__((ext_vector_type(8))) __bf16 bf16x8;
typedef __attribute__((ext_vector_type(4))) float  f32x4;

__device__ __forceinline__ void gload_lds16(const void* g, void* l) {
    __builtin_amdgcn_global_load_lds((const __attribute__((address_space(1))) unsigned int*)g,
                                     (__attribute__((address_space(3))) unsigned int*)l, 16, 0, 0);
}

__device__ __forceinline__ unsigned short f2bf(float x) {
    __hip_bfloat16 h = __float2bfloat16(x);
    return *(unsigned short*)&h;
}

// ---------- pack: image -> bf16-hi, tile-major K-chunk layout.
// Flat short index = ((tile*12 + kslot)*128 + rowin)*8 + e  == cid*8 + e.
// Byte-identical to the dist kernel's LDS layout -> staging is a linear memcpy.
__global__ void pack_kernel(const float* __restrict__ img, unsigned short* __restrict__ dst) {
    int cid = blockIdx.x * 256 + threadIdx.x;       // 0 .. 121*12*128-1
    int t   = cid / 1536;
    int rem = cid - t * 1536;
    int s   = rem >> 7;          // kslot 0..11
    int r   = rem & 127;         // row within tile
    int row = t * 128 + r;       // patch index (padded range)

    unsigned short ch8[8];
    #pragma unroll
    for (int e = 0; e < 8; ++e) {
        int k = s * 8 + e;
        unsigned short v = 0;
        if (row < NPATCH && k < 75) {
            int c  = k / 25, rem2 = k - c * 25;
            int di = rem2 / 5, dj = rem2 - di * 5;
            int pr = row / 124, pc = row - pr * 124;
            v = f2bf(img[c * 16384 + (pr + di) * 128 + (pc + dj)]);
        }
        ch8[e] = v;
    }
    *(ulonglong2*)(dst + (size_t)cid * 8) = *(ulonglong2*)ch8;
}

// ---------- squared norms straight from the image (exact f32)
__global__ void sqnorm_img(const float* __restrict__ img, float* __restrict__ out, int n) {
    int p = blockIdx.x * 256 + threadIdx.x;
    if (p >= n) return;
    if (p >= NPATCH) { out[p] = 3.0e38f; return; }
    int pr = p / 124, pc = p % 124;
    const float* base = img + pr * 128 + pc;
    float s = 0.f;
    #pragma unroll
    for (int ch = 0; ch < 3; ++ch)
        #pragma unroll
        for (int di = 0; di < 5; ++di)
            #pragma unroll
            for (int dj = 0; dj < 5; ++dj) {
                float v = base[ch * 16384 + di * 128 + dj];
                s = fmaf(v, v, s);
            }
    out[p] = s;
}

// ---------- MFMA hi-only dist screen: per (row, 128-col block) min of (Y2 - 2*dot_hi)
__global__ __launch_bounds__(256, 3)
void dist_mfma(const unsigned short* __restrict__ A, const unsigned short* __restrict__ B,
               const float* __restrict__ Y2, float* __restrict__ PM) {
    __shared__ __align__(16) unsigned short As[KS][128][8];   // 24 KB
    __shared__ __align__(16) unsigned short Bs[KS][128][8];   // 24 KB

    const int tid = threadIdx.x, lane = tid & 63, wid = tid >> 6;
    const int wr = wid >> 1, wc = wid & 1;

    // bijective XCD chunk swizzle (nwg = 14641 = 8*1830 + 1)
    const int orig = blockIdx.x;
    const int xcd = orig & 7, idx = orig >> 3;
    const int q = 1830, rm = 1;
    const int wg = ((xcd < rm) ? xcd * (q + 1) : rm * (q + 1) + (xcd - rm) * q) + idx;
    const int bx = wg % NT, by = wg / NT;   // bx = A row-tile (fast), by = B col-tile
    const int i0 = bx * 128, j0 = by * 128;

    // Stage both 24KB tiles linearly (global layout == LDS layout).
    const char* Ag = (const char*)(A + (size_t)bx * TILE_SHORTS);
    const char* Bg = (const char*)(B + (size_t)by * TILE_SHORTS);
    char* Al = (char*)&As[0][0][0];
    char* Bl = (char*)&Bs[0][0][0];
    #pragma unroll
    for (int i = 0; i < 6; ++i) {
        int v = wid * 6 + i;                  // 24 wave-loads of 1KB per matrix
        gload_lds16(Ag + v * 1024 + lane * 16, Al + v * 1024);
        gload_lds16(Bg + v * 1024 + lane * 16, Bl + v * 1024);
    }
    asm volatile("s_waitcnt vmcnt(0)" ::: "memory");
    __syncthreads();

    f32x4 acc[4][4];
    #pragma unroll
    for (int mi = 0; mi < 4; ++mi)
        #pragma unroll
        for (int ni = 0; ni < 4; ++ni)
            acc[mi][ni] = (f32x4){0.f, 0.f, 0.f, 0.f};

    #pragma unroll
    for (int ks = 0; ks < 3; ++ks) {
        bf16x8 a[4], b[4];
        #pragma unroll
        for (int mi = 0; mi < 4; ++mi)
            a[mi] = *(const bf16x8*)&As[ks * 4 + (lane >> 4)][wr * 64 + mi * 16 + (lane & 15)][0];
        #pragma unroll
        for (int ni = 0; ni < 4; ++ni)
            b[ni] = *(const bf16x8*)&Bs[ks * 4 + (lane >> 4)][wc * 64 + ni * 16 + (lane & 15)][0];
        #pragma unroll
        for (int mi = 0; mi < 4; ++mi)
            #pragma unroll
            for (int ni = 0; ni < 4; ++ni)
                acc[mi][ni] = __builtin_amdgcn_mfma_f32_16x16x32_bf16(a[mi], b[ni], acc[mi][ni], 0, 0, 0);
    }

    // Epilogue: d = Y2[col] - 2*acc; per-row min over this block's 128 cols.
    float y2v[4];
    #pragma unroll
    for (int ni = 0; ni < 4; ++ni)
        y2v[ni] = Y2[j0 + wc * 64 + ni * 16 + (lane & 15)];

    float* Ms = (float*)&As[0][0][0];   // 256 floats, As dead after barrier
    __syncthreads();
    #pragma unroll
    for (int mi = 0; mi < 4; ++mi) {
        #pragma unroll
        for (int j = 0; j < 4; ++j) {
            float m = fmaf(-2.f, acc[mi][0][j], y2v[0]);
            #pragma unroll
            for (int ni = 1; ni < 4; ++ni)
                m = fminf(m, fmaf(-2.f, acc[mi][ni][j], y2v[ni]));
            #pragma unroll
            for (int off = 1; off < 16; off <<= 1)
                m = fminf(m, __shfl_xor(m, off));
            if ((lane & 15) == 0)
                Ms[wc * 128 + wr * 64 + mi * 16 + (lane >> 4) * 4 + j] = m;
        }
    }
    __syncthreads();
    if (tid < 128) {
        float pm = fminf(Ms[tid], Ms[128 + tid]);
        PM[(size_t)by * NP + i0 + tid] = pm;
    }
}

// ---------- repair: one block per row; one exact f32 distance per thread
__global__ __launch_bounds__(256)
void repair_kernel(const float* __restrict__ crop, const float* __restrict__ orig,
                   const float* __restrict__ X2, const float* __restrict__ Y2,
                   const float* __restrict__ PM,
                   float* __restrict__ out, float* __restrict__ rsum) {
    __shared__ float xs[75];
    __shared__ float red[256];
    __shared__ int   list[NT];
    __shared__ int   cnt;
    __shared__ float wd[4];
    __shared__ int   wi[4];

    const int r = blockIdx.x;          // row 0..NPATCH-1
    const int tid = threadIdx.x;

    if (tid < 75) {
        int ch = tid / 25, rem = tid % 25, di = rem / 5, dj = rem % 5;
        int pr = r / 124, pc = r % 124;
        xs[tid] = crop[ch * 16384 + (pr + di) * 128 + (pc + dj)];
    }
    if (tid == 0) cnt = 0;

    // row min over the 121 tile minima
    float pm = (tid < NT) ? PM[(size_t)tid * NP + r] : 3.4e38f;
    red[tid] = pm;
    __syncthreads();
    #pragma unroll
    for (int s = 128; s > 0; s >>= 1) {
        if (tid < s) red[tid] = fminf(red[tid], red[tid + s]);
        __syncthreads();
    }
    const float mt = red[0];

    // flag & compact candidate tiles (order-independent: argmin is lexicographic)
    if (tid < NT && pm <= mt + EPS) {
        int p = atomicAdd(&cnt, 1);
        list[p] = tid;
    }
    __syncthreads();
    const int nc = cnt;
    const float x2 = X2[r];

    float bestd = 3.4e38f;
    int   besti = 0x7fffffff;
    const int col = tid & 127, slot = tid >> 7;
    for (int c = 0; c < nc; c += 2) {
        int cand = c + slot;
        if (cand < nc) {
            int j = list[cand] * 128 + col;
            if (j < NPATCH) {
                int jr = j / 124, jc = j % 124;
                const float* yb = orig + jr * 128 + jc;
                float dot = 0.f;
                #pragma unroll
                for (int ch = 0; ch < 3; ++ch)
                    #pragma unroll
                    for (int di = 0; di < 5; ++di)
                        #pragma unroll
                        for (int dj = 0; dj < 5; ++dj)
                            dot = fmaf(xs[ch * 25 + di * 5 + dj],
                                       yb[ch * 16384 + di * 128 + dj], dot);
                float d = fmaf(-2.f, dot, x2) + Y2[j];
                if (d < bestd || (d == bestd && j < besti)) { bestd = d; besti = j; }
            }
        }
    }

    // block argmin: wave shuffle reduce, then cross-wave via LDS
    #pragma unroll
    for (int off = 1; off < 64; off <<= 1) {
        float od = __shfl_xor(bestd, off);
        int   oi = __shfl_xor(besti, off);
        if (od < bestd || (od == bestd && oi < besti)) { bestd = od; besti = oi; }
    }
    const int lane = tid & 63, wid = tid >> 6;
    if (lane == 0) { wd[wid] = bestd; wi[wid] = besti; }
    __syncthreads();
    if (tid == 0) {
        float bd = wd[0]; int bi = wi[0];
        #pragma unroll
        for (int w = 1; w < 4; ++w)
            if (wd[w] < bd || (wd[w] == bd && wi[w] < bi)) { bd = wd[w]; bi = wi[w]; }
        out[1 + r] = (float)bi;
        rsum[r] = bd;
    }
}

// ---------- deterministic final loss (fixed-order strided sum + tree)
__global__ void loss_final(const float* __restrict__ rsum, float* __restrict__ out) {
    __shared__ float s[256];
    float acc = 0.f;
    for (int i = threadIdx.x; i < NPATCH; i += 256) acc += rsum[i];
    s[threadIdx.x] = acc;
    __syncthreads();
    for (int st = 128; st > 0; st >>= 1) {
        if (threadIdx.x < st) s[threadIdx.x] += s[threadIdx.x + st];
        __syncthreads();
    }
    if (threadIdx.x == 0) out[0] = s[0] / (float)NPATCH;
}

extern "C" void kernel_launch(void* const* d_in, const int* in_sizes, int n_in,
                              void* d_out, int out_size, void* d_ws, size_t ws_size,
                              hipStream_t stream) {
    const float* crop = (const float*)d_in[0];
    const float* orig = (const float*)d_in[1];
    float* out = (float*)d_out;

    unsigned short* Abig = (unsigned short*)d_ws;              // NT*12288 shorts
    unsigned short* Bbig = Abig + (size_t)NT * TILE_SHORTS;    // NT*12288 shorts
    float* X2 = (float*)(Bbig + (size_t)NT * TILE_SHORTS);     // NPATCH
    float* Y2 = X2 + NPATCH;                                   // NP (pads = 3e38)
    float* PM = Y2 + NP;                                       // NT*NP
    float* RS = PM + (size_t)NT * NP;                          // NPATCH

    pack_kernel<<<726, 256, 0, stream>>>(crop, Abig);
    pack_kernel<<<726, 256, 0, stream>>>(orig, Bbig);
    sqnorm_img<<<(NPATCH + 255) / 256, 256, 0, stream>>>(crop, X2, NPATCH);
    sqnorm_img<<<(NP + 255) / 256, 256, 0, stream>>>(orig, Y2, NP);

    dist_mfma<<<NT * NT, 256, 0, stream>>>(Abig, Bbig, Y2, PM);

    repair_kernel<<<NPATCH, 256, 0, stream>>>(crop, orig, X2, Y2, PM, out, RS);
    loss_final<<<1, 256, 0, stream>>>(RS, out);
}

// Round 7
// 199.109 us; speedup vs baseline: 2.7558x; 1.1041x over previous
//
#include <hip/hip_runtime.h>
#include <hip/hip_bf16.h>

#define NPATCH 15376       // 124*124 patches
#define NP     15488       // B rows padded: 121*128
#define NT     121         // B col-tiles (128 each)
#define ATILES 128         // A rows padded: 128*128 = 16384
#define TILE_SHORTS 12288  // 12*128*8 shorts per 128-row tile (24KB)
#define EPSA   2.0f        // acc-space flag margin (== EPS 4.0 in dist-space, validated r4-r6)
#define PMW    124         // PM row stride (121 used)

typedef __attribute__((ext_vector_type(8))) __bf16 bf16x8;
typedef __attribute__((ext_vector_type(4))) float  f32x4;

__device__ __forceinline__ void gload_lds16(const void* g, void* l) {
    __builtin_amdgcn_global_load_lds((const __attribute__((address_space(1))) unsigned int*)g,
                                     (__attribute__((address_space(3))) unsigned int*)l, 16, 0, 0);
}
__device__ __forceinline__ unsigned short f2bf(float x) {
    __hip_bfloat16 h = __float2bfloat16(x);
    return *(unsigned short*)&h;
}
__device__ __forceinline__ float bf2f(unsigned short u) {
    __hip_bfloat16 h; *(unsigned short*)&h = u;
    return __bfloat162float(h);
}
template<int CTRL>
__device__ __forceinline__ float dppmax(float x) {
    int xi = __builtin_bit_cast(int, x);
    int yi = __builtin_amdgcn_update_dpp(xi, xi, CTRL, 0xf, 0xf, true);
    return fmaxf(x, __builtin_bit_cast(float, yi));
}

// ---------- fused squared norms: Y2 (padded, 3e38 pads) and X2
__device__ __forceinline__ float patch_sq(const float* __restrict__ img, int p) {
    int pr = p / 124, pc = p - pr * 124;
    const float* base = img + pr * 128 + pc;
    float s = 0.f;
    #pragma unroll
    for (int ch = 0; ch < 3; ++ch)
        #pragma unroll
        for (int di = 0; di < 5; ++di)
            #pragma unroll
            for (int dj = 0; dj < 5; ++dj) {
                float v = base[ch * 16384 + di * 128 + dj];
                s = fmaf(v, v, s);
            }
    return s;
}
__global__ void sqnorm2(const float* __restrict__ crop, const float* __restrict__ orig,
                        float* __restrict__ X2, float* __restrict__ Y2) {
    int p = blockIdx.x * 256 + threadIdx.x;
    if (p < NP) {
        Y2[p] = (p < NPATCH) ? patch_sq(orig, p) : 3.0e38f;
    } else {
        int q = p - NP;
        if (q < NPATCH) X2[q] = patch_sq(crop, q);
    }
}

// ---------- pack both matrices: tile-major [tile][kslot12][row128][8] bf16.
// features 0..74 = bf16(patch); slot 75/76: A -> -0.5,-0.5 ; B -> Y2hi,Y2lo; 77..95 = 0.
__global__ void pack2(const float* __restrict__ crop, const float* __restrict__ orig,
                      unsigned short* __restrict__ Abig, unsigned short* __restrict__ Bbig,
                      const float* __restrict__ Y2) {
    int cid = blockIdx.x * 256 + threadIdx.x;     // 0 .. 128*1536 + 121*1536 - 1
    const float* img;
    unsigned short* dst;
    bool isA;
    if (cid < ATILES * 1536) { img = crop; dst = Abig; isA = true; }
    else { cid -= ATILES * 1536; img = orig; dst = Bbig; isA = false; }
    int t = cid / 1536, rem = cid - t * 1536;
    int s = rem >> 7, r = rem & 127;
    int row = t * 128 + r;
    unsigned short ch8[8];
    #pragma unroll
    for (int e = 0; e < 8; ++e) {
        int k = s * 8 + e;
        unsigned short v = 0;
        if (k < 75) {
            if (row < NPATCH) {
                int c = k / 25, rem2 = k - c * 25;
                int di = rem2 / 5, dj = rem2 - di * 5;
                int pr = row / 124, pc = row - pr * 124;
                v = f2bf(img[c * 16384 + (pr + di) * 128 + (pc + dj)]);
            }
        } else if (k < 77) {
            if (isA) v = f2bf(-0.5f);
            else {
                float yv = Y2[row];               // row < 15488
                unsigned short hi = f2bf(yv);
                v = (k == 75) ? hi : f2bf(yv - bf2f(hi));
            }
        }
        ch8[e] = v;
    }
    *(ulonglong2*)(dst + (size_t)cid * 8) = *(ulonglong2*)ch8;
}

// ---------- persistent-chunk MFMA screen: PM[row][tile] = max_cols(acc), acc = dot - Y2/2
__global__ __launch_bounds__(512, 2)
void dist_mfma3(const unsigned short* __restrict__ A, const unsigned short* __restrict__ B,
                float* __restrict__ PM) {
    __shared__ __align__(16) unsigned short Bs[2][12][128][8];  // 48 KB
    __shared__ __align__(16) float Red[2][512];                 // 4 KB

    const int tid = threadIdx.x, lane = tid & 63, wid = tid >> 6;
    const int rg = wid >> 1, cg = wid & 1;
    const int l15 = lane & 15, l4 = lane >> 4;
    const int chunk = blockIdx.x & 7, rowblk = blockIdx.x >> 3;   // chunk per XCD
    const int t0 = chunk * 15 + (chunk ? 1 : 0);
    const int nt = chunk ? 15 : 16;                               // 16+15*7 = 121
    const int rowbase = rowblk * 512;

#define STAGE(buf, tile)                                                          \
    {                                                                             \
        const char* _g = (const char*)(B + (size_t)(tile) * TILE_SHORTS);         \
        char* _l = (char*)&Bs[buf][0][0][0];                                      \
        _Pragma("unroll")                                                         \
        for (int _i = 0; _i < 3; ++_i)                                            \
            gload_lds16(_g + (tid + _i * 512) * 16, _l + (tid + _i * 512) * 16);  \
    }

    STAGE(0, t0);

    // A fragments: 24 bf16x8 (96 VGPR), direct global, one-time.
    // addr(shorts) = ((atile*12 + ks*4 + l4)*128 + mi*16 + l15)*8
    bf16x8 a[8][3];
    {
        const unsigned short* Abase =
            A + ((size_t)(rowblk * 4 + rg) * 12 + l4) * 1024 + (size_t)l15 * 8;
        #pragma unroll
        for (int mi = 0; mi < 8; ++mi)
            #pragma unroll
            for (int ks = 0; ks < 3; ++ks)
                a[mi][ks] = *(const bf16x8*)(Abase + ks * 4096 + mi * 128);
    }

    asm volatile("s_waitcnt vmcnt(0)" ::: "memory");
    __syncthreads();

    int cur = 0;
    for (int it = 0; it < nt; ++it) {
        if (it + 1 < nt) STAGE(cur ^ 1, t0 + it + 1);

        f32x4 acc[8][4];
        #pragma unroll
        for (int ks = 0; ks < 3; ++ks) {
            bf16x8 b[4];
            #pragma unroll
            for (int ni = 0; ni < 4; ++ni)
                b[ni] = *(const bf16x8*)&Bs[cur][ks * 4 + l4][cg * 64 + ni * 16 + l15][0];
            #pragma unroll
            for (int mi = 0; mi < 8; ++mi)
                #pragma unroll
                for (int ni = 0; ni < 4; ++ni)
                    acc[mi][ni] = __builtin_amdgcn_mfma_f32_16x16x32_bf16(
                        a[mi][ks], b[ni],
                        (ks == 0) ? (f32x4){0.f, 0.f, 0.f, 0.f} : acc[mi][ni], 0, 0, 0);
        }

        // per-row max over this wave's 64 cols: ni-fold + 4 DPP-max (16-lane groups)
        #pragma unroll
        for (int mi = 0; mi < 8; ++mi) {
            f32x4 m4;
            #pragma unroll
            for (int j = 0; j < 4; ++j) {
                float m = fmaxf(fmaxf(acc[mi][0][j], acc[mi][1][j]),
                                fmaxf(acc[mi][2][j], acc[mi][3][j]));
                m = dppmax<0xB1>(m);    // quad_perm [1,0,3,2]  (xor 1)
                m = dppmax<0x4E>(m);    // quad_perm [2,3,0,1]  (xor 2)
                m = dppmax<0x141>(m);   // row_half_mirror      (8-group)
                m = dppmax<0x140>(m);   // row_mirror           (16-group)
                m4[j] = m;
            }
            if (l15 == 0)
                *(f32x4*)&Red[cg][rg * 128 + mi * 16 + l4 * 4] = m4;
        }
        __syncthreads();
        {   // combine cg halves, store PM[row][tile]
            float v = fmaxf(Red[0][tid], Red[1][tid]);
            int grow = rowbase + tid;
            if (grow < NPATCH) PM[(size_t)grow * PMW + t0 + it] = v;
        }
        asm volatile("s_waitcnt vmcnt(0)" ::: "memory");
        __syncthreads();
        cur ^= 1;
    }
#undef STAGE
}

// ---------- repair: one block per row; coalesced PM row read; exact f32 argmin
__global__ __launch_bounds__(256)
void repair_kernel(const float* __restrict__ crop, const float* __restrict__ orig,
                   const float* __restrict__ X2, const float* __restrict__ Y2,
                   const float* __restrict__ PM,
                   float* __restrict__ out, float* __restrict__ rsum) {
    __shared__ float xs[75];
    __shared__ float red[256];
    __shared__ int   list[128];
    __shared__ int   cnt;
    __shared__ float wd[4];
    __shared__ int   wi[4];

    const int r = blockIdx.x;
    const int tid = threadIdx.x;

    if (tid < 75) {
        int ch = tid / 25, rem = tid % 25, di = rem / 5, dj = rem % 5;
        int pr = r / 124, pc = r % 124;
        xs[tid] = crop[ch * 16384 + (pr + di) * 128 + (pc + dj)];
    }
    if (tid == 0) cnt = 0;

    float pm = (tid < NT) ? PM[(size_t)r * PMW + tid] : -3.4e38f;
    red[tid] = pm;
    __syncthreads();
    #pragma unroll
    for (int s = 128; s > 0; s >>= 1) {
        if (tid < s) red[tid] = fmaxf(red[tid], red[tid + s]);
        __syncthreads();
    }
    const float MT = red[0];

    if (tid < NT && pm >= MT - EPSA) {
        int p = atomicAdd(&cnt, 1);
        list[p] = tid;
    }
    __syncthreads();
    const int nc = cnt;
    const float x2 = X2[r];

    float bestd = 3.4e38f;
    int   besti = 0x7fffffff;
    const int col = tid & 127, slot = tid >> 7;
    for (int c = 0; c < nc; c += 2) {
        int cand = c + slot;
        if (cand < nc) {
            int j = list[cand] * 128 + col;
            if (j < NPATCH) {
                int jr = j / 124, jc = j % 124;
                const float* yb = orig + jr * 128 + jc;
                float dot = 0.f;
                #pragma unroll
                for (int ch = 0; ch < 3; ++ch)
                    #pragma unroll
                    for (int di = 0; di < 5; ++di)
                        #pragma unroll
                        for (int dj = 0; dj < 5; ++dj)
                            dot = fmaf(xs[ch * 25 + di * 5 + dj],
                                       yb[ch * 16384 + di * 128 + dj], dot);
                float d = fmaf(-2.f, dot, x2) + Y2[j];
                if (d < bestd || (d == bestd && j < besti)) { bestd = d; besti = j; }
            }
        }
    }

    #pragma unroll
    for (int off = 1; off < 64; off <<= 1) {
        float od = __shfl_xor(bestd, off);
        int   oi = __shfl_xor(besti, off);
        if (od < bestd || (od == bestd && oi < besti)) { bestd = od; besti = oi; }
    }
    const int lane = tid & 63, wv = tid >> 6;
    if (lane == 0) { wd[wv] = bestd; wi[wv] = besti; }
    __syncthreads();
    if (tid == 0) {
        float bd = wd[0]; int bi = wi[0];
        #pragma unroll
        for (int w = 1; w < 4; ++w)
            if (wd[w] < bd || (wd[w] == bd && wi[w] < bi)) { bd = wd[w]; bi = wi[w]; }
        out[1 + r] = (float)bi;
        rsum[r] = bd;
    }
}

// ---------- deterministic final loss
__global__ void loss_final(const float* __restrict__ rsum, float* __restrict__ out) {
    __shared__ float s[256];
    float acc = 0.f;
    for (int i = threadIdx.x; i < NPATCH; i += 256) acc += rsum[i];
    s[threadIdx.x] = acc;
    __syncthreads();
    for (int st = 128; st > 0; st >>= 1) {
        if (threadIdx.x < st) s[threadIdx.x] += s[threadIdx.x + st];
        __syncthreads();
    }
    if (threadIdx.x == 0) out[0] = s[0] / (float)NPATCH;
}

extern "C" void kernel_launch(void* const* d_in, const int* in_sizes, int n_in,
                              void* d_out, int out_size, void* d_ws, size_t ws_size,
                              hipStream_t stream) {
    const float* crop = (const float*)d_in[0];
    const float* orig = (const float*)d_in[1];
    float* out = (float*)d_out;

    unsigned short* Abig = (unsigned short*)d_ws;               // 128*12288 shorts (3.15 MB)
    unsigned short* Bbig = Abig + (size_t)ATILES * TILE_SHORTS; // 121*12288 shorts (2.97 MB)
    float* X2 = (float*)(Bbig + (size_t)NT * TILE_SHORTS);      // NPATCH
    float* Y2 = X2 + NPATCH;                                    // NP (pads 3e38)
    float* PM = Y2 + NP;                                        // NPATCH*124 (7.63 MB)
    float* RS = PM + (size_t)NPATCH * PMW;                      // NPATCH

    sqnorm2<<<(NP + NPATCH + 255) / 256, 256, 0, stream>>>(crop, orig, X2, Y2);
    pack2<<<(ATILES + NT) * 6, 256, 0, stream>>>(crop, orig, Abig, Bbig, Y2);  // 1536/256=6
    dist_mfma3<<<256, 512, 0, stream>>>(Abig, Bbig, PM);
    repair_kernel<<<NPATCH, 256, 0, stream>>>(crop, orig, X2, Y2, PM, out, RS);
    loss_final<<<1, 256, 0, stream>>>(RS, out);
}